// Round 11
// baseline (730.567 us; speedup 1.0000x reference)
//
#include <hip/hip_runtime.h>
#include <math.h>

#define Tt 32
#define Bb 64
#define Ss 64
#define Ee 512
#define Hh 1024
#define Vv 32000
#define LEc 32
#define G4H 4096
#define Mm 2048   // T*B rows

typedef __bf16 bf16x8 __attribute__((ext_vector_type(8)));
typedef float f32x4 __attribute__((ext_vector_type(4)));
typedef short short4v __attribute__((ext_vector_type(4)));

__device__ __forceinline__ short f2bf(float f){
  unsigned u = __builtin_bit_cast(unsigned, f);
  u += 0x7fffu + ((u >> 16) & 1u);
  return (short)(u >> 16);
}

__device__ __forceinline__ void gl_lds16(const short* g, short* l){
  __builtin_amdgcn_global_load_lds((const __attribute__((address_space(1))) void*)g,
                                   (__attribute__((address_space(3))) void*)l, 16, 0, 0);
}

// ---------------- fused prep: hyper_w + hyper_b + embed + init_hc ----------------
__global__ __launch_bounds__(256) void k_prep(
    const float* __restrict__ Wih, const float* __restrict__ bihv,
    const float* __restrict__ Whh, const float* __restrict__ bhhv,
    const float* __restrict__ Wbih, const float* __restrict__ bbih,
    const float* __restrict__ Wbhh, const float* __restrict__ bbhh,
    const float* __restrict__ lang_embed, const int* __restrict__ lang_idx,
    const int* __restrict__ x, const float* __restrict__ vocab,
    const float* __restrict__ h0, const float* __restrict__ c0,
    short* __restrict__ w_ih, short* __restrict__ w_hh, float* __restrict__ b_total,
    short* __restrict__ emb, short* __restrict__ hbf, float* __restrict__ c)
{
  int blk = blockIdx.x;
  if (blk < 24576){
    const long NIH = (long)G4H * Ee;
    long r = (long)blk * 256 + threadIdx.x;
    const float4* el4 = (const float4*)(lang_embed + (size_t)lang_idx[0] * LEc);
    float4 e[8];
    #pragma unroll
    for (int j = 0; j < 8; j++) e[j] = el4[j];
    const float4* W4; float bb; short* outp;
    if (r < NIH){ W4 = (const float4*)(Wih + r * LEc); bb = bihv[r]; outp = w_ih + r; }
    else { long rr = r - NIH; W4 = (const float4*)(Whh + rr * LEc); bb = bhhv[rr]; outp = w_hh + rr; }
    float acc = bb;
    #pragma unroll
    for (int j = 0; j < 8; j++){
      float4 w = W4[j];
      acc += w.x*e[j].x + w.y*e[j].y + w.z*e[j].z + w.w*e[j].w;
    }
    *outp = f2bf(acc);
  } else if (blk < 24592){
    int u = (blk - 24576) * 256 + threadIdx.x;
    const float* el = lang_embed + (size_t)lang_idx[0] * LEc;
    float acc = bbih[u] + bbhh[u];
    #pragma unroll
    for (int j = 0; j < LEc; j++)
      acc += (Wbih[(size_t)u*LEc + j] + Wbhh[(size_t)u*LEc + j]) * el[j];
    b_total[u] = acc;
  } else if (blk < 25616){
    int tid = (blk - 24592) * 256 + threadIdx.x;
    int row = tid / (Ee / 4);
    int j4 = (tid % (Ee / 4)) * 4;
    int tok = x[row];
    float4 v = *(const float4*)(vocab + (size_t)tok * Ee + j4);
    short4v o = { f2bf(v.x), f2bf(v.y), f2bf(v.z), f2bf(v.w) };
    *(short4v*)(emb + (size_t)row * Ee + j4) = o;
  } else {
    int i = (blk - 25616) * 256 + threadIdx.x;
    hbf[i] = f2bf(h0[i]);
    c[i] = c0[i];
  }
}

// ---------------- m97 tiled MFMA GEMM (128x128, BK=32) for xgates / c2h ----------
template<int M, int N, int K, int MODE>
__global__ __launch_bounds__(256) void k_gemm(
    const short* __restrict__ A, const short* __restrict__ B,
    const float* __restrict__ bias, void* __restrict__ Cv)
{
  __shared__ short lA[4096];
  __shared__ short lB[4096];
  const int nwg = (M/128)*(N/128);
  int xcd = blockIdx.x & 7, pos = blockIdx.x >> 3;
  int wg = xcd * (nwg >> 3) + pos;
  const int MT = M/128;
  int mt = wg % MT;
  int nt = wg / MT;

  int t = threadIdx.x;
  int wave = t >> 6, lane = t & 63;
  int wm = wave >> 1, wn = wave & 1;
  int tr = t >> 2;
  int tc = (t & 3) * 8;

  const short* Agp = A + (size_t)(mt*128)*K;
  const short* Bgp = B + (size_t)(nt*128)*K;

  f32x4 acc[4][4];
  #pragma unroll
  for (int i = 0; i < 4; i++)
    #pragma unroll
    for (int j = 0; j < 4; j++) acc[i][j] = (f32x4){0.f,0.f,0.f,0.f};

  int ra = lane & 15, ko = (lane >> 4) * 8;

  for (int k0 = 0; k0 < K; k0 += 32){
    #pragma unroll
    for (int q2 = 0; q2 < 2; q2++){
      gl_lds16(Agp + (size_t)(q2*64 + tr)*K + k0 + tc, &lA[q2*2048 + wave*512]);
      gl_lds16(Bgp + (size_t)(q2*64 + tr)*K + k0 + tc, &lB[q2*2048 + wave*512]);
    }
    __syncthreads();
    bf16x8 av[4], bv[4];
    #pragma unroll
    for (int i = 0; i < 4; i++){
      av[i] = *(const bf16x8*)&lA[(wm*64 + i*16 + ra)*32 + ko];
      bv[i] = *(const bf16x8*)&lB[(wn*64 + i*16 + ra)*32 + ko];
    }
    #pragma unroll
    for (int i = 0; i < 4; i++)
      #pragma unroll
      for (int j = 0; j < 4; j++)
        acc[i][j] = __builtin_amdgcn_mfma_f32_16x16x32_bf16(av[i], bv[j], acc[i][j], 0, 0, 0);
    __syncthreads();
  }

  int col = lane & 15, r0 = (lane >> 4) * 4;
  #pragma unroll
  for (int i = 0; i < 4; i++)
    #pragma unroll
    for (int j = 0; j < 4; j++)
      #pragma unroll
      for (int q = 0; q < 4; q++){
        int m = mt*128 + wm*64 + i*16 + r0 + q;
        int n = nt*128 + wn*64 + j*16 + col;
        float v = acc[i][j][q] + bias[n];
        if (MODE == 0) ((float*)Cv)[(size_t)m * N + n] = v;
        else           ((short*)Cv)[(size_t)m * N + n] = f2bf(tanhf(v));
      }
}

// ---------------- h2o: 256x256 8-phase counted-vmcnt GEMM, persistent 2 tiles ----
// 500 blocks, m204-bijective XCD-chunked: 4 consecutive co-XCD blocks share each
// B n-panel (L2 panel sharing), each block does 2 m-tiles.
#define VMW4 asm volatile("s_waitcnt vmcnt(4)" ::: "memory")
#define VMW0 asm volatile("s_waitcnt vmcnt(0)" ::: "memory")
#define VMNONE ((void)0)

#define PHASE(d, lp, LOADB, VMW, ...) do { \
    bf16x8 afr[2][2]; \
    _Pragma("unroll") \
    for (int ii = 0; ii < 2; ii++){ \
      _Pragma("unroll") \
      for (int ks = 0; ks < 2; ks++){ \
        int r = (2*(lp)+ii)*16 + la15; \
        int sc = (ks*4 + l4) ^ (r & 7); \
        afr[ii][ks] = *(const bf16x8*)(lds + ((d)*2+wm)*16384 + (r*8+sc)*16); \
      } \
    } \
    if (LOADB){ \
      _Pragma("unroll") \
      for (int fj = 0; fj < 4; fj++){ \
        _Pragma("unroll") \
        for (int ks = 0; ks < 2; ks++){ \
          int grow = wn*64 + fj*16 + la15; \
          int hh = grow >> 7, rb = grow & 127; \
          int sc = (ks*4 + l4) ^ (rb & 7); \
          bfr[fj][ks] = *(const bf16x8*)(lds + 65536 + ((d)*2+hh)*16384 + (rb*8+sc)*16); \
        } \
      } \
    } \
    __VA_ARGS__; \
    __builtin_amdgcn_s_barrier(); \
    asm volatile("s_waitcnt lgkmcnt(0)" ::: "memory"); \
    __builtin_amdgcn_sched_barrier(0); \
    __builtin_amdgcn_s_setprio(1); \
    _Pragma("unroll") \
    for (int ii = 0; ii < 2; ii++){ \
      _Pragma("unroll") \
      for (int ks = 0; ks < 2; ks++){ \
        _Pragma("unroll") \
        for (int fj = 0; fj < 4; fj++){ \
          acc[2*(lp)+ii][fj] = __builtin_amdgcn_mfma_f32_16x16x32_bf16(afr[ii][ks], bfr[fj][ks], acc[2*(lp)+ii][fj], 0, 0, 0); \
        } \
      } \
    } \
    __builtin_amdgcn_s_setprio(0); \
    VMW; \
    __builtin_amdgcn_s_barrier(); \
  } while (0)

__global__ __launch_bounds__(512, 2) void k_h2o8(
    const short* __restrict__ A, const short* __restrict__ Bw,
    const float* __restrict__ bias, float* __restrict__ C)
{
  extern __shared__ char lds[];
  int tid = threadIdx.x;
  int wave = tid >> 6, lane = tid & 63;
  int wm = wave >> 2, wn = wave & 3;
  int la15 = lane & 15, l4 = lane >> 4;
  int col = lane & 15, r0 = (lane >> 4) * 4;

  // m204 bijective XCD-chunk over 500 wgs: q=62, r=4 (XCDs 0-3 get 63)
  int xcd = blockIdx.x & 7, pos = blockIdx.x >> 3;
  int wg = (xcd < 4 ? xcd * 63 : 4 * 63 + (xcd - 4) * 62) + pos;
  int nt  = wg >> 2;              // 0..124 (4 co-XCD blocks per panel)
  int mtb = (wg & 3) * 2;         // 0,2,4,6
  const short* Bg = Bw + (size_t)(nt*256)*Hh;

  for (int tp = 0; tp < 2; tp++){
    int mt = mtb + tp;
    const short* Ag = A + (size_t)(mt*256)*Hh;

    auto stage_half = [&](const short* G, int Xoff, int d, int h, int kt){
      #pragma unroll
      for (int call = 0; call < 2; call++){
        int chunk = call*512 + tid;
        int rr = chunk >> 3;
        int cc = (chunk & 7) ^ (rr & 7);
        const short* src = G + (size_t)(h*128 + rr)*Hh + kt*64 + cc*8;
        char* dst = lds + Xoff + (d*2+h)*16384 + call*8192 + wave*1024;
        gl_lds16(src, (short*)dst);
      }
    };

    f32x4 acc[8][4];
    #pragma unroll
    for (int i = 0; i < 8; i++)
      #pragma unroll
      for (int j = 0; j < 4; j++) acc[i][j] = (f32x4){0.f,0.f,0.f,0.f};
    bf16x8 bfr[4][2];

    stage_half(Ag, 0,     0, 0, 0); stage_half(Ag, 0,     0, 1, 0);
    stage_half(Bg, 65536, 0, 0, 0); stage_half(Bg, 65536, 0, 1, 0);
    stage_half(Bg, 65536, 1, 0, 1); stage_half(Bg, 65536, 1, 1, 1);
    VMW4;
    __builtin_amdgcn_s_barrier();

    for (int it = 0; it < 7; it++){
      int kt0 = 2*it;
      PHASE(0, 0, true,  VMNONE, stage_half(Ag, 0,     1, 0, kt0+1));
      PHASE(0, 1, false, VMNONE, stage_half(Ag, 0,     1, 1, kt0+1));
      PHASE(0, 2, false, VMNONE, stage_half(Bg, 65536, 0, 0, kt0+2));
      PHASE(0, 3, false, VMW4,   stage_half(Bg, 65536, 0, 1, kt0+2));
      PHASE(1, 0, true,  VMNONE, stage_half(Ag, 0,     0, 0, kt0+2));
      PHASE(1, 1, false, VMNONE, stage_half(Ag, 0,     0, 1, kt0+2));
      PHASE(1, 2, false, VMNONE, stage_half(Bg, 65536, 1, 0, kt0+3));
      PHASE(1, 3, false, VMW4,   stage_half(Bg, 65536, 1, 1, kt0+3));
    }
    PHASE(0, 0, true,  VMNONE, stage_half(Ag, 0, 1, 0, 15));
    PHASE(0, 1, false, VMNONE, stage_half(Ag, 0, 1, 1, 15));
    PHASE(0, 2, false, VMNONE, VMNONE);
    PHASE(0, 3, false, VMW0,   VMNONE);
    PHASE(1, 0, true,  VMNONE, VMNONE);
    PHASE(1, 1, false, VMNONE, VMNONE);
    PHASE(1, 2, false, VMNONE, VMNONE);
    PHASE(1, 3, false, VMNONE, VMNONE);

    #pragma unroll
    for (int fi = 0; fi < 8; fi++)
      #pragma unroll
      for (int fj = 0; fj < 4; fj++)
        #pragma unroll
        for (int q = 0; q < 4; q++){
          int m = mt*256 + wm*128 + fi*16 + r0 + q;
          int n = nt*256 + wn*64 + fj*16 + col;
          C[(size_t)m * Vv + n] = acc[fi][fj][q] + bias[n];
        }
  }
}

// ---------------- one LSTM step + piggyback f2bf conversion ----------------
#define PIG4 8716288L      // (Vv*Hh + Hh*2*Hh)/4 float4s
#define PIGQ 272384L       // PIG4/32
#define H2O4 8192000L      // Vv*Hh/4
__global__ __launch_bounds__(256) void k_step(
    int t, const short* __restrict__ h_in, const short* __restrict__ w_hh,
    const float* __restrict__ Gx, float* __restrict__ c,
    short* __restrict__ h_out, float* __restrict__ rnn_out, short* __restrict__ concat,
    const float* __restrict__ h2oW, short* __restrict__ h2oWb,
    const float* __restrict__ c2hW, short* __restrict__ c2hWb)
{
  if (blockIdx.x >= 256){
    long pb = blockIdx.x - 256;
    long base = (long)t * PIGQ;
    for (long i = pb*256 + threadIdx.x; i < PIGQ; i += 65536){
      long gi = base + i;
      const float* src; short* dst;
      if (gi < H2O4){ src = h2oW + gi*4; dst = h2oWb + gi*4; }
      else { long j = gi - H2O4; src = c2hW + j*4; dst = c2hWb + j*4; }
      float4 v = *(const float4*)src;
      short4v o = { f2bf(v.x), f2bf(v.y), f2bf(v.z), f2bf(v.w) };
      *(short4v*)dst = o;
    }
    return;
  }
  __shared__ float red[4][4][16][16];
  int mt = blockIdx.x >> 6;
  int n0 = (blockIdx.x & 63) * 16;
  int wv = threadIdx.x >> 6;
  int lane = threadIdx.x & 63;
  int ra = lane & 15, ko = (lane >> 4) * 8;
  f32x4 acc[4] = {{0,0,0,0},{0,0,0,0},{0,0,0,0},{0,0,0,0}};
  const short* Ap = h_in + (size_t)(mt*16 + ra) * Hh + wv*256 + ko;
  const short* Bp = w_hh + (size_t)(n0    + ra) * Hh + wv*256 + ko;
  #pragma unroll
  for (int kk = 0; kk < 256; kk += 32){
    bf16x8 a = *(const bf16x8*)(Ap + kk);
    #pragma unroll
    for (int g = 0; g < 4; g++){
      bf16x8 b = *(const bf16x8*)(Bp + (size_t)g*Hh*Hh + kk);
      acc[g] = __builtin_amdgcn_mfma_f32_16x16x32_bf16(a, b, acc[g], 0, 0, 0);
    }
  }
  int col = lane & 15, r0 = (lane >> 4) * 4;
  #pragma unroll
  for (int g = 0; g < 4; g++)
    #pragma unroll
    for (int i = 0; i < 4; i++)
      red[wv][g][r0 + i][col] = acc[g][i];
  __syncthreads();

  int r  = threadIdx.x >> 4;
  int cc = threadIdx.x & 15;
  int b  = mt*16 + r;
  int u  = n0 + cc;
  float gate[4];
  #pragma unroll
  for (int g = 0; g < 4; g++){
    float s = Gx[((size_t)t*Bb + b) * G4H + g*Hh + u];
    #pragma unroll
    for (int w2 = 0; w2 < 4; w2++) s += red[w2][g][r][cc];
    gate[g] = s;
  }
  float ig = 1.f / (1.f + expf(-gate[0]));
  float fg = 1.f / (1.f + expf(-gate[1]));
  float gg = tanhf(gate[2]);
  float og = 1.f / (1.f + expf(-gate[3]));
  size_t bu = (size_t)b * Hh + u;
  float cn = fg * c[bu] + ig * gg;
  c[bu] = cn;
  float hn = og * tanhf(cn);
  h_out[bu] = f2bf(hn);
  size_t row = (size_t)t * Bb + b;
  rnn_out[row * Hh + u] = hn;
  concat[row * (2*Hh) + Hh + u] = f2bf(hn);
}

// ---------------- fused attention: scores+softmax+context (+final copy) ----------
__global__ __launch_bounds__(256) void k_attn(
    const float* __restrict__ rnn_out, const float* __restrict__ src,
    const int* __restrict__ src_len, short* __restrict__ concat,
    const float* __restrict__ cbuf, float* __restrict__ out)
{
  if (blockIdx.x >= 256){
    int pb = blockIdx.x - 256;
    for (int i = pb*256 + threadIdx.x; i < Bb*Hh; i += 1024){
      out[(size_t)Mm * Vv + i]           = rnn_out[(size_t)(Tt-1)*Bb*Hh + i];
      out[(size_t)Mm * Vv + Bb*Hh + i]   = cbuf[i];
    }
    return;
  }
  __shared__ float srcL[64 * 129];
  __shared__ float rnnL[8 * 129];
  __shared__ float satt[8][64];

  int b  = blockIdx.x & 63;
  int t0 = (blockIdx.x >> 6) * 8;
  int tid = threadIdx.x;
  int wave = tid >> 6, lane = tid & 63;

  float sc0 = 0.f, sc1 = 0.f;
  for (int c0 = 0; c0 < Hh; c0 += 128){
    __syncthreads();
    for (int i = tid; i < 64*128; i += 256){
      int s = i >> 7, h = i & 127;
      srcL[s*129 + h] = src[((size_t)s*Bb + b) * Hh + c0 + h];
    }
    for (int i = tid; i < 8*128; i += 256){
      int rr = i >> 7, h = i & 127;
      rnnL[rr*129 + h] = rnn_out[((size_t)(t0+rr)*Bb + b) * Hh + c0 + h];
    }
    __syncthreads();
    const float* sp = &srcL[lane*129];
    const float* r0p = &rnnL[(2*wave)*129];
    const float* r1p = &rnnL[(2*wave+1)*129];
    #pragma unroll 8
    for (int h = 0; h < 128; h++){
      float sv = sp[h];
      sc0 += r0p[h] * sv;
      sc1 += r1p[h] * sv;
    }
  }
  int slen = src_len[b];
  if (lane >= slen){ sc0 = -1e30f; sc1 = -1e30f; }
  float mx0 = sc0, mx1 = sc1;
  for (int o = 32; o; o >>= 1){ mx0 = fmaxf(mx0, __shfl_xor(mx0, o, 64)); mx1 = fmaxf(mx1, __shfl_xor(mx1, o, 64)); }
  float p0 = expf(sc0 - mx0), p1 = expf(sc1 - mx1);
  float s0 = p0, s1 = p1;
  for (int o = 32; o; o >>= 1){ s0 += __shfl_xor(s0, o, 64); s1 += __shfl_xor(s1, o, 64); }
  satt[2*wave][lane]   = p0 / s0;
  satt[2*wave+1][lane] = p1 / s1;
  __syncthreads();

  int h0 = tid * 4;
  float4 acc[8];
  #pragma unroll
  for (int i = 0; i < 8; i++) acc[i] = make_float4(0.f, 0.f, 0.f, 0.f);
  for (int s = 0; s < Ss; s++){
    float4 sv = *(const float4*)(src + ((size_t)s*Bb + b) * Hh + h0);
    #pragma unroll
    for (int i = 0; i < 8; i++){
      float a = satt[i][s];
      acc[i].x += a*sv.x; acc[i].y += a*sv.y; acc[i].z += a*sv.z; acc[i].w += a*sv.w;
    }
  }
  #pragma unroll
  for (int i = 0; i < 8; i++){
    size_t row = (size_t)(t0 + i)*Bb + b;
    short4v o = { f2bf(acc[i].x), f2bf(acc[i].y), f2bf(acc[i].z), f2bf(acc[i].w) };
    *(short4v*)(concat + row * (2*Hh) + h0) = o;
  }
}

extern "C" void kernel_launch(void* const* d_in, const int* in_sizes, int n_in,
                              void* d_out, int out_size, void* d_ws, size_t ws_size,
                              hipStream_t stream) {
  const int*   x         = (const int*)  d_in[0];
  const int*   src_len   = (const int*)  d_in[1];
  const int*   lang_idx  = (const int*)  d_in[2];
  const float* h0        = (const float*)d_in[3];
  const float* c0        = (const float*)d_in[4];
  const float* src       = (const float*)d_in[5];
  const float* vocab     = (const float*)d_in[6];
  const float* lang_emb  = (const float*)d_in[7];
  const float* Wih       = (const float*)d_in[8];
  const float* bih       = (const float*)d_in[9];
  const float* Whh       = (const float*)d_in[10];
  const float* bhh       = (const float*)d_in[11];
  const float* Wbih      = (const float*)d_in[12];
  const float* bbih      = (const float*)d_in[13];
  const float* Wbhh      = (const float*)d_in[14];
  const float* bbhh      = (const float*)d_in[15];
  const float* c2hW      = (const float*)d_in[16];
  const float* c2hb      = (const float*)d_in[17];
  const float* h2oW      = (const float*)d_in[18];
  const float* h2ob      = (const float*)d_in[19];
  float* out = (float*)d_out;

  char* ws = (char*)d_ws;
  short* w_ih   = (short*)(ws + 0);
  short* w_hh   = (short*)(ws + 4194304);
  short* c2hWb  = (short*)(ws + 12582912);
  short* h2oWb  = (short*)(ws + 16777216);
  float* b_tot  = (float*)(ws + 82313216);
  short* emb    = (short*)(ws + 82329600);
  float* Gx     = (float*)(ws + 84426752);
  short* hb0    = (short*)(ws + 117981184);
  short* hb1    = (short*)(ws + 118112256);
  float* cbuf   = (float*)(ws + 118243328);
  float* rnn    = (float*)(ws + 118505472);
  short* concat = (short*)(ws + 126894080);
  short* ah     = (short*)(ws + 135806976);

  // fused prep (hypernet w/b + embed + init h/c)
  k_prep<<<25872, 256, 0, stream>>>(Wih, bih, Whh, bhh, Wbih, bbih, Wbhh, bbhh,
                                    lang_emb, lang_idx, x, vocab, h0, c0,
                                    w_ih, w_hh, b_tot, emb, hb0, cbuf);

  // x-path gates for all timesteps
  k_gemm<Mm, G4H, Ee, 0><<<(Mm/128)*(G4H/128), 256, 0, stream>>>(emb, w_ih, b_tot, Gx);

  // sequential LSTM scan (32 launches) + piggybacked f2bf of h2oW/c2hW
  short* hbuf[2] = { hb0, hb1 };
  for (int t = 0; t < Tt; t++){
    k_step<<<512, 256, 0, stream>>>(t, hbuf[t & 1], w_hh, Gx, cbuf,
                                    hbuf[(t + 1) & 1], rnn, concat,
                                    h2oW, h2oWb, c2hW, c2hWb);
  }

  // fused attention (scores+softmax+context) + hN/cN copy
  k_attn<<<260, 256, 0, stream>>>(rnn, src, src_len, concat, cbuf, out);

  // projections
  k_gemm<Mm, Hh, 2*Hh, 1><<<(Mm/128)*(Hh/128), 256, 0, stream>>>(concat, c2hWb, c2hb, ah);
  hipFuncSetAttribute((const void*)k_h2o8, hipFuncAttributeMaxDynamicSharedMemorySize, 131072);
  k_h2o8<<<500, 512, 131072, stream>>>(ah, h2oWb, h2ob, out);
}

// Round 12
// 723.937 us; speedup vs baseline: 1.0092x; 1.0092x over previous
//
#include <hip/hip_runtime.h>
#include <math.h>

#define Tt 32
#define Bb 64
#define Ss 64
#define Ee 512
#define Hh 1024
#define Vv 32000
#define LEc 32
#define G4H 4096
#define Mm 2048   // T*B rows

typedef __bf16 bf16x8 __attribute__((ext_vector_type(8)));
typedef float f32x4 __attribute__((ext_vector_type(4)));
typedef short short4v __attribute__((ext_vector_type(4)));

__device__ __forceinline__ short f2bf(float f){
  unsigned u = __builtin_bit_cast(unsigned, f);
  u += 0x7fffu + ((u >> 16) & 1u);
  return (short)(u >> 16);
}

__device__ __forceinline__ void gl_lds16(const short* g, short* l){
  __builtin_amdgcn_global_load_lds((const __attribute__((address_space(1))) void*)g,
                                   (__attribute__((address_space(3))) void*)l, 16, 0, 0);
}

// ---------------- fused prep: hyper_w + hyper_b + embed + init_hc ----------------
__global__ __launch_bounds__(256) void k_prep(
    const float* __restrict__ Wih, const float* __restrict__ bihv,
    const float* __restrict__ Whh, const float* __restrict__ bhhv,
    const float* __restrict__ Wbih, const float* __restrict__ bbih,
    const float* __restrict__ Wbhh, const float* __restrict__ bbhh,
    const float* __restrict__ lang_embed, const int* __restrict__ lang_idx,
    const int* __restrict__ x, const float* __restrict__ vocab,
    const float* __restrict__ h0, const float* __restrict__ c0,
    short* __restrict__ w_ih, short* __restrict__ w_hh, float* __restrict__ b_total,
    short* __restrict__ emb, short* __restrict__ hbf, float* __restrict__ c)
{
  int blk = blockIdx.x;
  if (blk < 24576){
    const long NIH = (long)G4H * Ee;
    long r = (long)blk * 256 + threadIdx.x;
    const float4* el4 = (const float4*)(lang_embed + (size_t)lang_idx[0] * LEc);
    float4 e[8];
    #pragma unroll
    for (int j = 0; j < 8; j++) e[j] = el4[j];
    const float4* W4; float bb; short* outp;
    if (r < NIH){ W4 = (const float4*)(Wih + r * LEc); bb = bihv[r]; outp = w_ih + r; }
    else { long rr = r - NIH; W4 = (const float4*)(Whh + rr * LEc); bb = bhhv[rr]; outp = w_hh + rr; }
    float acc = bb;
    #pragma unroll
    for (int j = 0; j < 8; j++){
      float4 w = W4[j];
      acc += w.x*e[j].x + w.y*e[j].y + w.z*e[j].z + w.w*e[j].w;
    }
    *outp = f2bf(acc);
  } else if (blk < 24592){
    int u = (blk - 24576) * 256 + threadIdx.x;
    const float* el = lang_embed + (size_t)lang_idx[0] * LEc;
    float acc = bbih[u] + bbhh[u];
    #pragma unroll
    for (int j = 0; j < LEc; j++)
      acc += (Wbih[(size_t)u*LEc + j] + Wbhh[(size_t)u*LEc + j]) * el[j];
    b_total[u] = acc;
  } else if (blk < 25616){
    int tid = (blk - 24592) * 256 + threadIdx.x;
    int row = tid / (Ee / 4);
    int j4 = (tid % (Ee / 4)) * 4;
    int tok = x[row];
    float4 v = *(const float4*)(vocab + (size_t)tok * Ee + j4);
    short4v o = { f2bf(v.x), f2bf(v.y), f2bf(v.z), f2bf(v.w) };
    *(short4v*)(emb + (size_t)row * Ee + j4) = o;
  } else {
    int i = (blk - 25616) * 256 + threadIdx.x;
    hbf[i] = f2bf(h0[i]);
    c[i] = c0[i];
  }
}

// ---------------- m97 tiled MFMA GEMM (128x128, BK=32) for xgates / c2h ----------
template<int M, int N, int K, int MODE>
__global__ __launch_bounds__(256) void k_gemm(
    const short* __restrict__ A, const short* __restrict__ B,
    const float* __restrict__ bias, void* __restrict__ Cv)
{
  __shared__ short lA[4096];
  __shared__ short lB[4096];
  const int nwg = (M/128)*(N/128);
  int xcd = blockIdx.x & 7, pos = blockIdx.x >> 3;
  int wg = xcd * (nwg >> 3) + pos;
  const int MT = M/128;
  int mt = wg % MT;
  int nt = wg / MT;

  int t = threadIdx.x;
  int wave = t >> 6, lane = t & 63;
  int wm = wave >> 1, wn = wave & 1;
  int tr = t >> 2;
  int tc = (t & 3) * 8;

  const short* Agp = A + (size_t)(mt*128)*K;
  const short* Bgp = B + (size_t)(nt*128)*K;

  f32x4 acc[4][4];
  #pragma unroll
  for (int i = 0; i < 4; i++)
    #pragma unroll
    for (int j = 0; j < 4; j++) acc[i][j] = (f32x4){0.f,0.f,0.f,0.f};

  int ra = lane & 15, ko = (lane >> 4) * 8;

  for (int k0 = 0; k0 < K; k0 += 32){
    #pragma unroll
    for (int q2 = 0; q2 < 2; q2++){
      gl_lds16(Agp + (size_t)(q2*64 + tr)*K + k0 + tc, &lA[q2*2048 + wave*512]);
      gl_lds16(Bgp + (size_t)(q2*64 + tr)*K + k0 + tc, &lB[q2*2048 + wave*512]);
    }
    __syncthreads();
    bf16x8 av[4], bv[4];
    #pragma unroll
    for (int i = 0; i < 4; i++){
      av[i] = *(const bf16x8*)&lA[(wm*64 + i*16 + ra)*32 + ko];
      bv[i] = *(const bf16x8*)&lB[(wn*64 + i*16 + ra)*32 + ko];
    }
    #pragma unroll
    for (int i = 0; i < 4; i++)
      #pragma unroll
      for (int j = 0; j < 4; j++)
        acc[i][j] = __builtin_amdgcn_mfma_f32_16x16x32_bf16(av[i], bv[j], acc[i][j], 0, 0, 0);
    __syncthreads();
  }

  int col = lane & 15, r0 = (lane >> 4) * 4;
  #pragma unroll
  for (int i = 0; i < 4; i++)
    #pragma unroll
    for (int j = 0; j < 4; j++)
      #pragma unroll
      for (int q = 0; q < 4; q++){
        int m = mt*128 + wm*64 + i*16 + r0 + q;
        int n = nt*128 + wn*64 + j*16 + col;
        float v = acc[i][j][q] + bias[n];
        if (MODE == 0) ((float*)Cv)[(size_t)m * N + n] = v;
        else           ((short*)Cv)[(size_t)m * N + n] = f2bf(tanhf(v));
      }
}

// ---------------- h2o: 256x256 8-phase counted-vmcnt GEMM, persistent 4 tiles ----
#define VMW4 asm volatile("s_waitcnt vmcnt(4)" ::: "memory")
#define VMW0 asm volatile("s_waitcnt vmcnt(0)" ::: "memory")
#define VMNONE ((void)0)

#define PHASE(d, lp, LOADB, VMW, ...) do { \
    bf16x8 afr[2][2]; \
    _Pragma("unroll") \
    for (int ii = 0; ii < 2; ii++){ \
      _Pragma("unroll") \
      for (int ks = 0; ks < 2; ks++){ \
        int r = (2*(lp)+ii)*16 + la15; \
        int sc = (ks*4 + l4) ^ (r & 7); \
        afr[ii][ks] = *(const bf16x8*)(lds + ((d)*2+wm)*16384 + (r*8+sc)*16); \
      } \
    } \
    if (LOADB){ \
      _Pragma("unroll") \
      for (int fj = 0; fj < 4; fj++){ \
        _Pragma("unroll") \
        for (int ks = 0; ks < 2; ks++){ \
          int grow = wn*64 + fj*16 + la15; \
          int hh = grow >> 7, rb = grow & 127; \
          int sc = (ks*4 + l4) ^ (rb & 7); \
          bfr[fj][ks] = *(const bf16x8*)(lds + 65536 + ((d)*2+hh)*16384 + (rb*8+sc)*16); \
        } \
      } \
    } \
    __VA_ARGS__; \
    __builtin_amdgcn_s_barrier(); \
    asm volatile("s_waitcnt lgkmcnt(0)" ::: "memory"); \
    __builtin_amdgcn_sched_barrier(0); \
    __builtin_amdgcn_s_setprio(1); \
    _Pragma("unroll") \
    for (int ii = 0; ii < 2; ii++){ \
      _Pragma("unroll") \
      for (int ks = 0; ks < 2; ks++){ \
        _Pragma("unroll") \
        for (int fj = 0; fj < 4; fj++){ \
          acc[2*(lp)+ii][fj] = __builtin_amdgcn_mfma_f32_16x16x32_bf16(afr[ii][ks], bfr[fj][ks], acc[2*(lp)+ii][fj], 0, 0, 0); \
        } \
      } \
    } \
    __builtin_amdgcn_s_setprio(0); \
    VMW; \
    __builtin_amdgcn_s_barrier(); \
  } while (0)

__global__ __launch_bounds__(512, 2) void k_h2o8(
    const short* __restrict__ A, const short* __restrict__ Bw,
    const float* __restrict__ bias, float* __restrict__ C)
{
  extern __shared__ char lds[];
  int tid = threadIdx.x;
  int wave = tid >> 6, lane = tid & 63;
  int wm = wave >> 2, wn = wave & 3;
  int la15 = lane & 15, l4 = lane >> 4;
  int col = lane & 15, r0 = (lane >> 4) * 4;

  int nt  = blockIdx.x >> 1;        // 0..124
  int mtb = (blockIdx.x & 1) * 4;   // 0 or 4
  const short* Bg = Bw + (size_t)(nt*256)*Hh;

  for (int tp = 0; tp < 4; tp++){
    int mt = mtb + tp;
    const short* Ag = A + (size_t)(mt*256)*Hh;

    auto stage_half = [&](const short* G, int Xoff, int d, int h, int kt){
      #pragma unroll
      for (int call = 0; call < 2; call++){
        int chunk = call*512 + tid;
        int rr = chunk >> 3;
        int cc = (chunk & 7) ^ (rr & 7);
        const short* src = G + (size_t)(h*128 + rr)*Hh + kt*64 + cc*8;
        char* dst = lds + Xoff + (d*2+h)*16384 + call*8192 + wave*1024;
        gl_lds16(src, (short*)dst);
      }
    };

    f32x4 acc[8][4];
    #pragma unroll
    for (int i = 0; i < 8; i++)
      #pragma unroll
      for (int j = 0; j < 4; j++) acc[i][j] = (f32x4){0.f,0.f,0.f,0.f};
    bf16x8 bfr[4][2];

    stage_half(Ag, 0,     0, 0, 0); stage_half(Ag, 0,     0, 1, 0);
    stage_half(Bg, 65536, 0, 0, 0); stage_half(Bg, 65536, 0, 1, 0);
    stage_half(Bg, 65536, 1, 0, 1); stage_half(Bg, 65536, 1, 1, 1);
    VMW4;
    __builtin_amdgcn_s_barrier();

    for (int it = 0; it < 7; it++){
      int kt0 = 2*it;
      PHASE(0, 0, true,  VMNONE, stage_half(Ag, 0,     1, 0, kt0+1));
      PHASE(0, 1, false, VMNONE, stage_half(Ag, 0,     1, 1, kt0+1));
      PHASE(0, 2, false, VMNONE, stage_half(Bg, 65536, 0, 0, kt0+2));
      PHASE(0, 3, false, VMW4,   stage_half(Bg, 65536, 0, 1, kt0+2));
      PHASE(1, 0, true,  VMNONE, stage_half(Ag, 0,     0, 0, kt0+2));
      PHASE(1, 1, false, VMNONE, stage_half(Ag, 0,     0, 1, kt0+2));
      PHASE(1, 2, false, VMNONE, stage_half(Bg, 65536, 1, 0, kt0+3));
      PHASE(1, 3, false, VMW4,   stage_half(Bg, 65536, 1, 1, kt0+3));
    }
    PHASE(0, 0, true,  VMNONE, stage_half(Ag, 0, 1, 0, 15));
    PHASE(0, 1, false, VMNONE, stage_half(Ag, 0, 1, 1, 15));
    PHASE(0, 2, false, VMNONE, VMNONE);
    PHASE(0, 3, false, VMW0,   VMNONE);
    PHASE(1, 0, true,  VMNONE, VMNONE);
    PHASE(1, 1, false, VMNONE, VMNONE);
    PHASE(1, 2, false, VMNONE, VMNONE);
    PHASE(1, 3, false, VMNONE, VMNONE);

    #pragma unroll
    for (int fi = 0; fi < 8; fi++)
      #pragma unroll
      for (int fj = 0; fj < 4; fj++)
        #pragma unroll
        for (int q = 0; q < 4; q++){
          int m = mt*256 + wm*128 + fi*16 + r0 + q;
          int n = nt*256 + wn*64 + fj*16 + col;
          C[(size_t)m * Vv + n] = acc[fi][fj][q] + bias[n];
        }
  }
}

// ---------------- one LSTM step + piggyback f2bf conversion ----------------
#define PIG4 8716288L      // (Vv*Hh + Hh*2*Hh)/4 float4s
#define PIGQ 272384L       // PIG4/32
#define H2O4 8192000L      // Vv*Hh/4
__global__ __launch_bounds__(256) void k_step(
    int t, const short* __restrict__ h_in, const short* __restrict__ w_hh,
    const float* __restrict__ Gx, float* __restrict__ c,
    short* __restrict__ h_out, float* __restrict__ rnn_out, short* __restrict__ concat,
    const float* __restrict__ h2oW, short* __restrict__ h2oWb,
    const float* __restrict__ c2hW, short* __restrict__ c2hWb)
{
  if (blockIdx.x >= 256){
    long pb = blockIdx.x - 256;
    long base = (long)t * PIGQ;
    for (long i = pb*256 + threadIdx.x; i < PIGQ; i += 65536){
      long gi = base + i;
      const float* src; short* dst;
      if (gi < H2O4){ src = h2oW + gi*4; dst = h2oWb + gi*4; }
      else { long j = gi - H2O4; src = c2hW + j*4; dst = c2hWb + j*4; }
      float4 v = *(const float4*)src;
      short4v o = { f2bf(v.x), f2bf(v.y), f2bf(v.z), f2bf(v.w) };
      *(short4v*)dst = o;
    }
    return;
  }
  __shared__ float red[4][4][16][16];
  int mt = blockIdx.x >> 6;
  int n0 = (blockIdx.x & 63) * 16;
  int wv = threadIdx.x >> 6;
  int lane = threadIdx.x & 63;
  int ra = lane & 15, ko = (lane >> 4) * 8;
  f32x4 acc[4] = {{0,0,0,0},{0,0,0,0},{0,0,0,0},{0,0,0,0}};
  const short* Ap = h_in + (size_t)(mt*16 + ra) * Hh + wv*256 + ko;
  const short* Bp = w_hh + (size_t)(n0    + ra) * Hh + wv*256 + ko;
  #pragma unroll
  for (int kk = 0; kk < 256; kk += 32){
    bf16x8 a = *(const bf16x8*)(Ap + kk);
    #pragma unroll
    for (int g = 0; g < 4; g++){
      bf16x8 b = *(const bf16x8*)(Bp + (size_t)g*Hh*Hh + kk);
      acc[g] = __builtin_amdgcn_mfma_f32_16x16x32_bf16(a, b, acc[g], 0, 0, 0);
    }
  }
  int col = lane & 15, r0 = (lane >> 4) * 4;
  #pragma unroll
  for (int g = 0; g < 4; g++)
    #pragma unroll
    for (int i = 0; i < 4; i++)
      red[wv][g][r0 + i][col] = acc[g][i];
  __syncthreads();

  int r  = threadIdx.x >> 4;
  int cc = threadIdx.x & 15;
  int b  = mt*16 + r;
  int u  = n0 + cc;
  float gate[4];
  #pragma unroll
  for (int g = 0; g < 4; g++){
    float s = Gx[((size_t)t*Bb + b) * G4H + g*Hh + u];
    #pragma unroll
    for (int w2 = 0; w2 < 4; w2++) s += red[w2][g][r][cc];
    gate[g] = s;
  }
  float ig = 1.f / (1.f + expf(-gate[0]));
  float fg = 1.f / (1.f + expf(-gate[1]));
  float gg = tanhf(gate[2]);
  float og = 1.f / (1.f + expf(-gate[3]));
  size_t bu = (size_t)b * Hh + u;
  float cn = fg * c[bu] + ig * gg;
  c[bu] = cn;
  float hn = og * tanhf(cn);
  h_out[bu] = f2bf(hn);
  size_t row = (size_t)t * Bb + b;
  rnn_out[row * Hh + u] = hn;
  concat[row * (2*Hh) + Hh + u] = f2bf(hn);
}

// ---------------- fused attention: scores+softmax+context (+final copy) ----------
__global__ __launch_bounds__(256) void k_attn(
    const float* __restrict__ rnn_out, const float* __restrict__ src,
    const int* __restrict__ src_len, short* __restrict__ concat,
    const float* __restrict__ cbuf, float* __restrict__ out)
{
  if (blockIdx.x >= 256){
    int pb = blockIdx.x - 256;
    for (int i = pb*256 + threadIdx.x; i < Bb*Hh; i += 1024){
      out[(size_t)Mm * Vv + i]           = rnn_out[(size_t)(Tt-1)*Bb*Hh + i];
      out[(size_t)Mm * Vv + Bb*Hh + i]   = cbuf[i];
    }
    return;
  }
  __shared__ float srcL[64 * 129];
  __shared__ float rnnL[8 * 129];
  __shared__ float satt[8][64];

  int b  = blockIdx.x & 63;
  int t0 = (blockIdx.x >> 6) * 8;
  int tid = threadIdx.x;
  int wave = tid >> 6, lane = tid & 63;

  float sc0 = 0.f, sc1 = 0.f;
  for (int c0 = 0; c0 < Hh; c0 += 128){
    __syncthreads();
    for (int i = tid; i < 64*128; i += 256){
      int s = i >> 7, h = i & 127;
      srcL[s*129 + h] = src[((size_t)s*Bb + b) * Hh + c0 + h];
    }
    for (int i = tid; i < 8*128; i += 256){
      int rr = i >> 7, h = i & 127;
      rnnL[rr*129 + h] = rnn_out[((size_t)(t0+rr)*Bb + b) * Hh + c0 + h];
    }
    __syncthreads();
    const float* sp = &srcL[lane*129];
    const float* r0p = &rnnL[(2*wave)*129];
    const float* r1p = &rnnL[(2*wave+1)*129];
    #pragma unroll 8
    for (int h = 0; h < 128; h++){
      float sv = sp[h];
      sc0 += r0p[h] * sv;
      sc1 += r1p[h] * sv;
    }
  }
  int slen = src_len[b];
  if (lane >= slen){ sc0 = -1e30f; sc1 = -1e30f; }
  float mx0 = sc0, mx1 = sc1;
  for (int o = 32; o; o >>= 1){ mx0 = fmaxf(mx0, __shfl_xor(mx0, o, 64)); mx1 = fmaxf(mx1, __shfl_xor(mx1, o, 64)); }
  float p0 = expf(sc0 - mx0), p1 = expf(sc1 - mx1);
  float s0 = p0, s1 = p1;
  for (int o = 32; o; o >>= 1){ s0 += __shfl_xor(s0, o, 64); s1 += __shfl_xor(s1, o, 64); }
  satt[2*wave][lane]   = p0 / s0;
  satt[2*wave+1][lane] = p1 / s1;
  __syncthreads();

  int h0 = tid * 4;
  float4 acc[8];
  #pragma unroll
  for (int i = 0; i < 8; i++) acc[i] = make_float4(0.f, 0.f, 0.f, 0.f);
  for (int s = 0; s < Ss; s++){
    float4 sv = *(const float4*)(src + ((size_t)s*Bb + b) * Hh + h0);
    #pragma unroll
    for (int i = 0; i < 8; i++){
      float a = satt[i][s];
      acc[i].x += a*sv.x; acc[i].y += a*sv.y; acc[i].z += a*sv.z; acc[i].w += a*sv.w;
    }
  }
  #pragma unroll
  for (int i = 0; i < 8; i++){
    size_t row = (size_t)(t0 + i)*Bb + b;
    short4v o = { f2bf(acc[i].x), f2bf(acc[i].y), f2bf(acc[i].z), f2bf(acc[i].w) };
    *(short4v*)(concat + row * (2*Hh) + h0) = o;
  }
}

extern "C" void kernel_launch(void* const* d_in, const int* in_sizes, int n_in,
                              void* d_out, int out_size, void* d_ws, size_t ws_size,
                              hipStream_t stream) {
  const int*   x         = (const int*)  d_in[0];
  const int*   src_len   = (const int*)  d_in[1];
  const int*   lang_idx  = (const int*)  d_in[2];
  const float* h0        = (const float*)d_in[3];
  const float* c0        = (const float*)d_in[4];
  const float* src       = (const float*)d_in[5];
  const float* vocab     = (const float*)d_in[6];
  const float* lang_emb  = (const float*)d_in[7];
  const float* Wih       = (const float*)d_in[8];
  const float* bih       = (const float*)d_in[9];
  const float* Whh       = (const float*)d_in[10];
  const float* bhh       = (const float*)d_in[11];
  const float* Wbih      = (const float*)d_in[12];
  const float* bbih      = (const float*)d_in[13];
  const float* Wbhh      = (const float*)d_in[14];
  const float* bbhh      = (const float*)d_in[15];
  const float* c2hW      = (const float*)d_in[16];
  const float* c2hb      = (const float*)d_in[17];
  const float* h2oW      = (const float*)d_in[18];
  const float* h2ob      = (const float*)d_in[19];
  float* out = (float*)d_out;

  char* ws = (char*)d_ws;
  short* w_ih   = (short*)(ws + 0);
  short* w_hh   = (short*)(ws + 4194304);
  short* c2hWb  = (short*)(ws + 12582912);
  short* h2oWb  = (short*)(ws + 16777216);
  float* b_tot  = (float*)(ws + 82313216);
  short* emb    = (short*)(ws + 82329600);
  float* Gx     = (float*)(ws + 84426752);
  short* hb0    = (short*)(ws + 117981184);
  short* hb1    = (short*)(ws + 118112256);
  float* cbuf   = (float*)(ws + 118243328);
  float* rnn    = (float*)(ws + 118505472);
  short* concat = (short*)(ws + 126894080);
  short* ah     = (short*)(ws + 135806976);

  // fused prep (hypernet w/b + embed + init h/c)
  k_prep<<<25872, 256, 0, stream>>>(Wih, bih, Whh, bhh, Wbih, bbih, Wbhh, bbhh,
                                    lang_emb, lang_idx, x, vocab, h0, c0,
                                    w_ih, w_hh, b_tot, emb, hb0, cbuf);

  // x-path gates for all timesteps
  k_gemm<Mm, G4H, Ee, 0><<<(Mm/128)*(G4H/128), 256, 0, stream>>>(emb, w_ih, b_tot, Gx);

  // sequential LSTM scan (32 launches) + piggybacked f2bf of h2oW/c2hW
  short* hbuf[2] = { hb0, hb1 };
  for (int t = 0; t < Tt; t++){
    k_step<<<512, 256, 0, stream>>>(t, hbuf[t & 1], w_hh, Gx, cbuf,
                                    hbuf[(t + 1) & 1], rnn, concat,
                                    h2oW, h2oWb, c2hW, c2hWb);
  }

  // fused attention (scores+softmax+context) + hN/cN copy
  k_attn<<<260, 256, 0, stream>>>(rnn, src, src_len, concat, cbuf, out);

  // projections
  k_gemm<Mm, Hh, 2*Hh, 1><<<(Mm/128)*(Hh/128), 256, 0, stream>>>(concat, c2hWb, c2hb, ah);
  hipFuncSetAttribute((const void*)k_h2o8, hipFuncAttributeMaxDynamicSharedMemorySize, 131072);
  k_h2o8<<<250, 512, 131072, stream>>>(ah, h2oWb, h2ob, out);
}